// Round 5
// baseline (14542.668 us; speedup 1.0000x reference)
//
#include <hip/hip_runtime.h>
#include <hip/hip_cooperative_groups.h>
namespace cg = cooperative_groups;

// ---------------- problem constants ----------------
constexpr int M_LZ = 96;           // Lanczos steps

// CSR capacity per matrix (expected nnz * ~1.25)
constexpr int CAP_L0 = 26240, CAP_L1 = 118016, CAP_L2 = 52480, CAP_B1 = 39360, CAP_B2 = 78720;
constexpr int CB_L0 = 0;
constexpr int CB_L1D = CB_L0 + CAP_L0;
constexpr int CB_L1U = CB_L1D + CAP_L1;
constexpr int CB_L2  = CB_L1U + CAP_L1;
constexpr int CB_B1  = CB_L2 + CAP_L2;
constexpr int CB_B2  = CB_B1 + CAP_B1;
constexpr int CAP_TOT= CB_B2 + CAP_B2;   // 432832
constexpr int CB_B1T = CAP_TOT;
constexpr int CB_B2T = CB_B1T + CAP_B1;
constexpr int CAP_TOT2 = CB_B2T + CAP_B2; // 550912

// rowptr offsets (ints) within W_PTR region
constexpr int P_L0=0, P_L1D=1025, P_L1U=4098, P_L2=7171, P_B1=9220, P_B2=10245;
constexpr int P_B1T=13320, P_B2T=16393;   // region size 18444
// row-count offsets within W_CNT region
constexpr int C_L0=0, C_L1D=1024, C_L1U=4096, C_L2=7168, C_B1=9216, C_B2=10240;
constexpr int C_B1T=13312, C_B2T=16384;   // region size 18432

// workspace layout (units: 4-byte words)
constexpr size_t W_CNT = 0;                         // 18432 ints
constexpr size_t W_PTR = 18432;                     // 18444 ints
constexpr size_t W_CUR = W_PTR + 18444;             // 5120 ints (B1T cursor @0, B2T @3072)
constexpr size_t W_CIDX= W_CUR + 5120;              // CAP_TOT2 ints
constexpr size_t W_VAL = W_CIDX + CAP_TOT2;         // CAP_TOT2 floats
constexpr size_t W_V   = W_VAL + CAP_TOT2;          // 5 slots * 6144 (v0,v1,v2, w0,w1)
constexpr size_t W_ACC = W_V + 5*6144;              // M_LZ*144 (16-bucket dot accumulators)
constexpr size_t W_EPS = W_ACC + (size_t)M_LZ*144;  // 4
constexpr size_t W_UV  = W_EPS + 4;                 // 4*3072 (U_d,V_d,U_u,V_u)
constexpr size_t HBUF  = (size_t)6144*128;
constexpr size_t W_H   = W_UV + 4*3072;             // 2 ping-pong harmonic buffers
constexpr size_t W_SCAT= W_H + 2*HBUF;
constexpr size_t S0_OFF= 0;                          // 1024 x 384
constexpr size_t S1_OFF= (size_t)1024*384;           // 3072 x 640
constexpr size_t S2_OFF= S1_OFF + (size_t)3072*640;  // 2048 x 384
constexpr size_t SCAT_TOT = S2_OFF + (size_t)2048*384;
constexpr size_t W_WCAT= W_SCAT + SCAT_TOT;          // 1408*128 concatenated weights
constexpr size_t WC0=0, WC1=(size_t)384*128, WC2=WC1+(size_t)640*128;

__device__ __forceinline__ float wredf(float v){
  #pragma unroll
  for(int o=32;o;o>>=1) v += __shfl_xor(v,o,64);
  return v;
}
__device__ __forceinline__ int wredi(int v){
  #pragma unroll
  for(int o=32;o;o>>=1) v += __shfl_xor(v,o,64);
  return v;
}

// ---------------- weight prep + zeroing of atomic counters/accumulators ----------------
__global__ void k_wprep(const float* Wd,const float* Wu,const float* Wh,
                        const float* Wb1,const float* Wb2, float* ws){
  int t = blockIdx.x*256 + threadIdx.x;
  if (t >= 16384) return;
  int* wsi = (int*)ws;
  if (t < 5120) wsi[W_CNT + 13312 + t] = 0;          // transpose col counters
  if (t < 5120) wsi[W_CUR + t] = 0;                  // cursors
  if (t < (int)(M_LZ*144)) ws[W_ACC + t] = 0.f;      // lanczos dot buckets
  float sd = Wd[t]  + Wd[16384+t]  + Wd[32768+t];
  float su = Wu[t]  + Wu[16384+t]  + Wu[32768+t];
  float s1 = Wb1[t] + Wb1[16384+t] + Wb1[32768+t];
  float s2 = Wb2[t] + Wb2[16384+t] + Wb2[32768+t];
  float wh = Wh[t];
  float* W0 = ws + W_WCAT + WC0;
  float* W1 = ws + W_WCAT + WC1;
  float* W2 = ws + W_WCAT + WC2;
  W0[t]=sd; W0[16384+t]=s1; W0[32768+t]=wh;                       // [Wd;Wb1;Wh]
  W1[t]=sd; W1[16384+t]=su; W1[32768+t]=s1; W1[49152+t]=s2; W1[65536+t]=wh; // [Wd;Wu;Wb1;Wb2;Wh]
  W2[t]=su; W2[16384+t]=s2; W2[32768+t]=wh;                       // [Wu;Wb2;Wh]
}

// ---------------- CSR extraction ----------------
__device__ __forceinline__ void mat_meta(int wid, const float* L0,const float* L1d,const float* L1u,
    const float* L2,const float* B1,const float* B2,
    const float*& M,int& ncol,int& lrow,int& co,int& po,int& cb,int& cap,int& tco){
  if (wid < 1024){ M=L0;  ncol=1024; lrow=wid;        co=C_L0;  po=P_L0;  cb=CB_L0;  cap=CAP_L0; tco=-1; }
  else if (wid < 4096){ M=L1d; ncol=3072; lrow=wid-1024;  co=C_L1D; po=P_L1D; cb=CB_L1D; cap=CAP_L1; tco=-1; }
  else if (wid < 7168){ M=L1u; ncol=3072; lrow=wid-4096;  co=C_L1U; po=P_L1U; cb=CB_L1U; cap=CAP_L1; tco=-1; }
  else if (wid < 9216){ M=L2;  ncol=2048; lrow=wid-7168;  co=C_L2;  po=P_L2;  cb=CB_L2;  cap=CAP_L2; tco=-1; }
  else if (wid < 10240){ M=B1; ncol=3072; lrow=wid-9216;  co=C_B1;  po=P_B1;  cb=CB_B1;  cap=CAP_B1; tco=C_B1T; }
  else { M=B2; ncol=2048; lrow=wid-10240; co=C_B2;  po=P_B2;  cb=CB_B2;  cap=CAP_B2; tco=C_B2T; }
}

__global__ void k_count(const float* L0,const float* L1d,const float* L1u,const float* L2,
                        const float* B1,const float* B2,int* cnt){
  int wid = blockIdx.x*4 + (threadIdx.x>>6);
  int lane = threadIdx.x & 63;
  if (wid >= 13312) return;
  const float* M; int ncol,lrow,co,po,cb,cap,tco;
  mat_meta(wid,L0,L1d,L1u,L2,B1,B2,M,ncol,lrow,co,po,cb,cap,tco);
  const float4* row4 = (const float4*)(M + (size_t)lrow*ncol);
  int c = 0;
  for (int j0=0; j0<ncol; j0+=256){
    float4 v = row4[(j0>>2)+lane];
    int n0=v.x!=0.f, n1=v.y!=0.f, n2=v.z!=0.f, n3=v.w!=0.f;
    c += n0+n1+n2+n3;
    if (tco>=0){
      int jb = j0 + lane*4;
      if (n0) atomicAdd(cnt+tco+jb,   1);
      if (n1) atomicAdd(cnt+tco+jb+1, 1);
      if (n2) atomicAdd(cnt+tco+jb+2, 1);
      if (n3) atomicAdd(cnt+tco+jb+3, 1);
    }
  }
  c = wredi(c);
  if (lane==0) cnt[co+lrow] = c;
}

__global__ void k_prefix(const int* cnt, int* ptr, int* cur){
  __shared__ int lds[257];
  const int rows[8]={1024,3072,3072,2048,1024,3072,3072,2048};
  const int cofs[8]={C_L0,C_L1D,C_L1U,C_L2,C_B1,C_B2,C_B1T,C_B2T};
  const int pofs[8]={P_L0,P_L1D,P_L1U,P_L2,P_B1,P_B2,P_B1T,P_B2T};
  int b=blockIdx.x, t=threadIdx.x;
  int R=rows[b]; const int* c=cnt+cofs[b]; int* p=ptr+pofs[b];
  int* cc = (b==6)? cur : (b==7)? cur+3072 : nullptr;
  int chunk=(R+255)/256;
  int lo=t*chunk, hi=min(R,lo+chunk);
  int s=0;
  for(int i=lo;i<hi;i++) s+=c[i];
  lds[t]=s; __syncthreads();
  if(t==0){ int run=0; for(int i=0;i<256;i++){int x=lds[i];lds[i]=run;run+=x;} lds[256]=run; }
  __syncthreads();
  int run=lds[t];
  for(int i=lo;i<hi;i++){ p[i]=run; if(cc) cc[i]=run; run+=c[i]; }
  if(t==0) p[R]=lds[256];
}

__global__ void k_fill(const float* L0,const float* L1d,const float* L1u,const float* L2,
                       const float* B1,const float* B2,const int* ptr,int* cidx,float* val){
  int wid = blockIdx.x*4 + (threadIdx.x>>6);
  int lane = threadIdx.x & 63;
  if (wid >= 13312) return;
  const float* M; int ncol,lrow,co,po,cb,cap,tco;
  mat_meta(wid,L0,L1d,L1u,L2,B1,B2,M,ncol,lrow,co,po,cb,cap,tco);
  const float4* row4 = (const float4*)(M + (size_t)lrow*ncol);
  int base = ptr[po+lrow];
  int run = 0;
  for (int j0=0; j0<ncol; j0+=256){
    float4 v = row4[(j0>>2)+lane];
    int n0=v.x!=0.f, n1=v.y!=0.f, n2=v.z!=0.f, n3=v.w!=0.f;
    int local = n0+n1+n2+n3;
    int incl = local;
    #pragma unroll
    for (int o=1;o<64;o<<=1){
      int tmp = __shfl_up(incl,o,64);
      if (lane>=o) incl += tmp;
    }
    int tot = __shfl(incl,63,64);
    int pos = base + run + incl - local;
    int jb = j0 + lane*4;
    if (n0){ if(pos<cap){cidx[cb+pos]=jb;   val[cb+pos]=v.x;} pos++; }
    if (n1){ if(pos<cap){cidx[cb+pos]=jb+1; val[cb+pos]=v.y;} pos++; }
    if (n2){ if(pos<cap){cidx[cb+pos]=jb+2; val[cb+pos]=v.z;} pos++; }
    if (n3){ if(pos<cap){cidx[cb+pos]=jb+3; val[cb+pos]=v.w;} pos++; }
    run += tot;
  }
}

// ---------------- CSR -> CSC (CSR of B1^T, B2^T) via cursor atomics ----------------
__global__ void k_fillT(float* ws){
  int wid = blockIdx.x*4 + (threadIdx.x>>6);
  int lane = threadIdx.x & 63;
  if (wid >= 4096) return;
  int* wsi=(int*)ws;
  const int* ptr=wsi+W_PTR; int* cidx=wsi+W_CIDX; float* val=ws+W_VAL;
  int* cur=wsi+W_CUR;
  if (wid < 1024){           // B1 rows -> B1T
    int r=wid;
    int e=ptr[P_B1+r+1];
    for(int k=ptr[P_B1+r]+lane;k<e;k+=64){
      int c=cidx[CB_B1+k]; float v=val[CB_B1+k];
      int pos=atomicAdd(cur+c,1);
      cidx[CB_B1T+pos]=r; val[CB_B1T+pos]=v;
    }
  } else {                   // B2 rows -> B2T
    int r=wid-1024;
    int e=ptr[P_B2+r+1];
    for(int k=ptr[P_B2+r]+lane;k<e;k+=64){
      int c=cidx[CB_B2+k]; float v=val[CB_B2+k];
      int pos=atomicAdd(cur+3072+c,1);
      cidx[CB_B2T+pos]=r; val[CB_B2T+pos]=v;
    }
  }
}

// ================= THE FUSED COOPERATIVE SOLVER =================
// 1024 blocks x 256 threads (4 blocks/CU). Wave gw owns rows gw and gw+4096.
// Single 10.4 KB shared buffer aliased across phases (grid.sync separates them):
// LDS was 23.6 KB in round 4 -> coop validation rejected 1024 blocks (2/CU model).
__global__ __launch_bounds__(256,4) void k_solve(float* ws,
    const float* z0,const float* z1,const float* z2,
    const float* adw,const float* adb,const float* auw,const float* aub,
    float* out){
  cg::grid_group grid = cg::this_grid();
  const int b = blockIdx.x, t = threadIdx.x;
  const int wv = t>>6, lane = t&63;
  const int gw = b*4 + wv;                 // 0..4095
  const int* wsi=(const int*)ws;
  const int* ptr=wsi+W_PTR; const int* cidx=wsi+W_CIDX; const float* val=ws+W_VAL;

  __shared__ float smem[2592];             // 10368 B, aliased per phase
  float* sABG = smem;                      // [3][3]   (phase B)
  float* redm = smem + 12;                 // [2][3][4](phase B)
  float* sp   = smem + 40;                 // [48][3]  (phase B)
  float* TTa  = smem;                      // [3][96]  (phase C, block 0)
  float* TTb  = smem + 288;                // [3][96]
  float* Sl   = smem;                      // [32][17] (phase E)
  float* Wl   = smem + 544;                // [16][128]

  // ---- Phase A: init lanczos vectors + attention U,V ----
  { int i = b*256+t;
    if (i < 6144){
      float invs = (i<1024)?0.03125f:(i<4096)?0.0180421959f:0.0220970869f;
      unsigned u=(unsigned)i*2654435761u; u^=u>>16; u*=2246822519u; u^=u>>13;
      ws[W_V+i] = (u&1)?invs:-invs;          // v0 (slot 0)
    } else if (i < 18432){
      ws[W_V+i] = 0.f;                       // v-slots 1,2 = 0
    }
  }
  if (gw < 3072){
    float2 x  = ((const float2*)(z1+(size_t)gw*128))[lane];
    float2 a0 = ((const float2*)adw)[lane];
    float2 a1 = ((const float2*)adw)[64+lane];
    float2 b0 = ((const float2*)auw)[lane];
    float2 b1 = ((const float2*)auw)[64+lane];
    float ud=x.x*a0.x+x.y*a0.y, vd=x.x*a1.x+x.y*a1.y;
    float uu=x.x*b0.x+x.y*b0.y, vu=x.x*b1.x+x.y*b1.y;
    ud=wredf(ud); vd=wredf(vd); uu=wredf(uu); vu=wredf(vu);
    if(lane==0){ ws[W_UV+gw]=ud; ws[W_UV+3072+gw]=vd; ws[W_UV+6144+gw]=uu; ws[W_UV+9216+gw]=vu; }
  }
  grid.sync();

  // row ownership (block-uniform complexes: boundaries 1024,4096 are multiples of 4)
  const int cA = (b<256)?0:1;          // complex of row1
  const int p1 = gw - (cA?1024:0);
  const int nb1 = cA?1024:0;
  const bool has2 = (b<512);           // row2 = gw+4096 in [4096,6144)
  const int p2 = gw;

  // ---- Phase B: 96 merged Lanczos steps ----
  for (int j=0;j<M_LZ;j++){
    if (j==0){
      if (t<3){ sABG[t*3+0]=0.f; sABG[t*3+1]=0.f; sABG[t*3+2]=1.f; }
    } else {
      if (t<48){
        int c=t>>4, bk=t&15;
        const float* A = ws + W_ACC + (size_t)(j-1)*144 + c*48;
        sp[t*3+0]=A[bk]; sp[t*3+1]=A[16+bk]; sp[t*3+2]=A[32+bk];
      }
      __syncthreads();
      if (t<3){
        float a=0.f,g=0.f,n=0.f;
        #pragma unroll
        for(int i=0;i<16;i++){ a+=sp[(t*16+i)*3+0]; g+=sp[(t*16+i)*3+1]; n+=sp[(t*16+i)*3+2]; }
        float beta = sqrtf(fmaxf(n-a*a-g*g,1e-20f));
        sABG[t*3+0]=a; sABG[t*3+1]=g; sABG[t*3+2]=1.f/beta;
      }
    }
    __syncthreads();
    auto dorow = [&](int c,int p,int nbase,int grp){
      float a=sABG[c*3+0], g=sABG[c*3+1], ib=sABG[c*3+2];
      float* vcur       = ws + W_V + (size_t)(j%3)*6144 + nbase;
      const float* vm1  = ws + W_V + (size_t)((j+2)%3)*6144 + nbase;
      const float* vm2  = ws + W_V + (size_t)((j+1)%3)*6144 + nbase;
      const float* wprev= ws + W_V + (size_t)(3+((j+1)&1))*6144 + nbase;
      float* wcur       = ws + W_V + (size_t)(3+(j&1))*6144 + nbase;
      float wp=0.f;
      #define GATHER(PP,CBB) { \
        const int* rp = ptr + PP; int e=rp[p+1]; \
        for (int k=rp[p]+lane; k<e; k+=64){ \
          int q = cidx[CBB+k]; float v = val[CBB+k]; \
          float vq = (j==0)? vcur[q] : (wprev[q] - a*vm1[q] - g*vm2[q])*ib; \
          wp += v*vq; \
        } }
      if (c==0){ GATHER(P_L0, CB_L0) }
      else if (c==1){ GATHER(P_L1D, CB_L1D) GATHER(P_L1U, CB_L1U) }
      else { GATHER(P_L2, CB_L2) }
      #undef GATHER
      wp = wredf(wp);
      if (lane==0){
        float vp;
        if (j==0) vp = vcur[p];
        else { vp = (wprev[p] - a*vm1[p] - g*vm2[p])*ib; vcur[p] = vp; }
        wcur[p] = wp;
        redm[grp*12 + 0*4 + wv]=vp*wp;
        redm[grp*12 + 1*4 + wv]=vm1[p]*wp;
        redm[grp*12 + 2*4 + wv]=wp*wp;
      }
    };
    dorow(cA, p1, nb1, 0);
    if (has2) dorow(2, p2, 4096, 1);
    __syncthreads();
    if (t==0){
      int bkt = b & 15;
      float* acc = ws + W_ACC + (size_t)j*144;
      float A0=redm[0]+redm[1]+redm[2]+redm[3];
      float G0=redm[4]+redm[5]+redm[6]+redm[7];
      float N0=redm[8]+redm[9]+redm[10]+redm[11];
      atomicAdd(acc + cA*48 +      bkt, A0);
      atomicAdd(acc + cA*48 + 16 + bkt, G0);
      atomicAdd(acc + cA*48 + 32 + bkt, N0);
      if (has2){
        float A2=redm[12]+redm[13]+redm[14]+redm[15];
        float G2=redm[16]+redm[17]+redm[18]+redm[19];
        float N2=redm[20]+redm[21]+redm[22]+redm[23];
        atomicAdd(acc + 2*48 +      bkt, A2);
        atomicAdd(acc + 2*48 + 16 + bkt, G2);
        atomicAdd(acc + 2*48 + 32 + bkt, N2);
      }
    }
    grid.sync();
  }

  // ---- Phase C: eig (block 0) + forward SpMMs (all) ----
  if (b==0){
    if (t<192){
      int c=t>>6;
      for (int i=lane;i<M_LZ;i+=64){
        const float* A = ws + W_ACC + (size_t)i*144 + c*48;
        float a=0.f,g=0.f,n=0.f;
        #pragma unroll
        for(int k2=0;k2<16;k2++){ a+=A[k2]; g+=A[16+k2]; n+=A[32+k2]; }
        TTa[c*M_LZ+i]=a; TTb[c*M_LZ+i]=sqrtf(fmaxf(n-a*a-g*g,1e-20f));
      }
    }
    __syncthreads();
    if (t<192){
      int c=t>>6;
      const float* TA=TTa+c*M_LZ; const float* TB=TTb+c*M_LZ;
      double lo=1e300, hi=-1e300;
      for (int i=lane;i<M_LZ;i+=64){
        double r=(i? fabs((double)TB[i-1]):0.0) + (i<M_LZ-1? fabs((double)TB[i]):0.0);
        lo=fmin(lo,(double)TA[i]-r); hi=fmax(hi,(double)TA[i]+r);
      }
      #pragma unroll
      for(int o=32;o;o>>=1){ lo=fmin(lo,__shfl_xor(lo,o,64)); hi=fmax(hi,__shfl_xor(hi,o,64)); }
      lo -= 1.0; hi += 1.0;
      for (int round=0; round<4; round++){
        double x = lo + (hi-lo)*(double)(lane+1)/65.0;
        double d = 1.0; int cnt2=0;
        for (int i=0;i<M_LZ;i++){
          double bi = i? (double)TB[i-1] : 0.0;
          d = ((double)TA[i]-x) - bi*bi/d;
          if (d==0.0) d = -1e-300;
          if (d<0.0) cnt2++;
        }
        double nlo = (cnt2< M_LZ)? x : -1e300;
        double nhi = (cnt2==M_LZ)? x :  1e300;
        #pragma unroll
        for(int o=32;o;o>>=1){ nlo=fmax(nlo,__shfl_xor(nlo,o,64)); nhi=fmin(nhi,__shfl_xor(nhi,o,64)); }
        if (nlo>-1e299) lo=nlo;
        if (nhi< 1e299) hi=nhi;
      }
      double lam = 0.5*(lo+hi);
      if (lane==0) ws[W_EPS+c] = (lam>0.0)? (float)(1.0/lam) : 0.1f;
    }
  }
  // forward SpMMs (tasks 0..18431, incl. attention-valued + transposes)
  for (int wid2 = gw; wid2 < 18432; wid2 += 4096){
    int task,p;
    if(wid2<1024){task=0;p=wid2;}
    else if(wid2<2048){task=1;p=wid2-1024;}
    else if(wid2<5120){task=2;p=wid2-2048;}
    else if(wid2<8192){task=3;p=wid2-5120;}
    else if(wid2<11264){task=4;p=wid2-8192;}
    else if(wid2<13312){task=5;p=wid2-11264;}
    else if(wid2<16384){task=6;p=wid2-13312;}
    else {task=7;p=wid2-16384;}
    const float* in; const int* rp; int cb2; float* outp; int ostride;
    int mode=0; float Vp=0.f, bb=0.f; const float* U=nullptr;
    switch(task){
      case 0: rp=ptr+P_L0;  cb2=CB_L0;  in=z0; outp=ws+W_SCAT+S0_OFF+0;   ostride=384; break;
      case 1: rp=ptr+P_B1;  cb2=CB_B1;  in=z1; outp=ws+W_SCAT+S0_OFF+128; ostride=384; break;
      case 2: rp=ptr+P_L1D; cb2=CB_L1D; in=z1; outp=ws+W_SCAT+S1_OFF+0;   ostride=640;
              mode=1; U=ws+W_UV; Vp=ws[W_UV+3072+p]; bb=adb[0]; break;
      case 3: rp=ptr+P_L1U; cb2=CB_L1U; in=z1; outp=ws+W_SCAT+S1_OFF+128; ostride=640;
              mode=1; U=ws+W_UV+6144; Vp=ws[W_UV+9216+p]; bb=aub[0]; break;
      case 4: rp=ptr+P_B2;  cb2=CB_B2;  in=z2; outp=ws+W_SCAT+S1_OFF+384; ostride=640; break;
      case 5: rp=ptr+P_L2;  cb2=CB_L2;  in=z2; outp=ws+W_SCAT+S2_OFF+0;   ostride=384; break;
      case 6: rp=ptr+P_B1T; cb2=CB_B1T; in=z0; outp=ws+W_SCAT+S1_OFF+256; ostride=640; break;
      default:rp=ptr+P_B2T; cb2=CB_B2T; in=z1; outp=ws+W_SCAT+S2_OFF+128; ostride=384; break;
    }
    float2 s={0.f,0.f};
    int e=rp[p+1];
    for (int k=rp[p]; k<e; k++){
      int q = cidx[cb2+k];
      float v;
      if (mode) v = 1.0f/(1.0f+__expf(-(U[q]+Vp+bb)));
      else v = val[cb2+k];
      float2 xq = ((const float2*)(in+(size_t)q*128))[lane];
      s.x += v*xq.x; s.y += v*xq.y;
    }
    ((float2*)(outp + (size_t)p*ostride))[lane] = s;
  }
  grid.sync();

  // ---- Phase D: 16 harmonic steps ----
  auto harm_row = [&](int c,int p,int step){
    const float* z = (c==0)?z0:(c==1)?z1:z2;
    float eps = ws[W_EPS+c];
    size_t cb2 = (c==0)? 0 : (c==1)? (size_t)1024*128 : (size_t)4096*128;
    const float* in = (step==0)? z : ws + W_H + (size_t)((step-1)&1)*HBUF + cb2;
    float* outp; size_t ostride;
    if (step<15){ outp = ws + W_H + (size_t)(step&1)*HBUF + cb2; ostride=128; }
    else {
      if(c==0){ outp=ws+W_SCAT+S0_OFF+256; ostride=384; }
      else if(c==1){ outp=ws+W_SCAT+S1_OFF+512; ostride=640; }
      else { outp=ws+W_SCAT+S2_OFF+256; ostride=384; }
    }
    float2 acc = ((const float2*)(in + (size_t)p*128))[lane];
    float2 s = {0.f,0.f};
    #define HGATHER(PP,CBB) { \
      const int* rp=ptr+PP; int e=rp[p+1]; \
      for(int k=rp[p];k<e;k++){ \
        float v=val[CBB+k]; int q=cidx[CBB+k]; \
        float2 xq=((const float2*)(in+(size_t)q*128))[lane]; \
        s.x+=v*xq.x; s.y+=v*xq.y; \
      } }
    if (c==0){ HGATHER(P_L0, CB_L0) }
    else if (c==1){ HGATHER(P_L1D, CB_L1D) HGATHER(P_L1U, CB_L1U) }
    else { HGATHER(P_L2, CB_L2) }
    #undef HGATHER
    acc.x -= eps*s.x; acc.y -= eps*s.y;
    ((float2*)(outp + (size_t)p*ostride))[lane] = acc;
  };
  for (int s=0;s<16;s++){
    harm_row(cA, p1, s);
    if (has2) harm_row(2, p2, s);
    grid.sync();
  }

  // ---- Phase E: projection GEMMs (blocks 0..191), K-tile 16 ----
  if (b < 192){
    const float* S; const float* W; float* outp; int K; int blk;
    if (b<32){       S=ws+W_SCAT+S0_OFF; W=ws+W_WCAT+WC0; outp=out;        K=384; blk=b; }
    else if (b<128){ S=ws+W_SCAT+S1_OFF; W=ws+W_WCAT+WC1; outp=out+131072; K=640; blk=b-32; }
    else {           S=ws+W_SCAT+S2_OFF; W=ws+W_WCAT+WC2; outp=out+524288; K=384; blk=b-128; }
    int r0=blk*32;
    int ty=t>>5, tx=t&31;
    float acc[4][4]={};
    for (int k0=0; k0<K; k0+=16){
      {
        int r=t>>3, kq=(t&7)*2;
        const float* src=S+(size_t)(r0+r)*K + k0+kq;
        Sl[r*17+kq]=src[0]; Sl[r*17+kq+1]=src[1];
      }
      {
        int kk=t>>4, cq=(t&15)*8;
        const float* src=W+(size_t)(k0+kk)*128+cq;
        #pragma unroll
        for(int i=0;i<8;i++) Wl[kk*128+cq+i]=src[i];
      }
      __syncthreads();
      #pragma unroll
      for(int k=0;k<16;k++){
        float sv[4], wvv[4];
        #pragma unroll
        for(int i=0;i<4;i++) sv[i]=Sl[(ty*4+i)*17+k];
        #pragma unroll
        for(int i=0;i<4;i++) wvv[i]=Wl[k*128+tx+32*i];
        #pragma unroll
        for(int a=0;a<4;a++)
          #pragma unroll
          for(int b2=0;b2<4;b2++) acc[a][b2]+=sv[a]*wvv[b2];
      }
      __syncthreads();
    }
    #pragma unroll
    for(int a=0;a<4;a++)
      #pragma unroll
      for(int b2=0;b2<4;b2++){
        int r=r0+ty*4+a, col=tx+32*b2;
        outp[(size_t)r*128+col]=fmaxf(acc[a][b2],0.f);
      }
  }
}

// ================= FALLBACK multi-kernel path (round-3 proven) =================
__global__ void k_init(float* ws){
  int i = blockIdx.x*256 + threadIdx.x;   // 72 blocks * 256 = 18432
  if (i < 6144){
    float invs;
    if (i<1024) invs = 0.03125f;
    else if (i<4096) invs = 0.0180421959f;
    else invs = 0.0220970869f;
    unsigned u = (unsigned)i*2654435761u; u^=u>>16; u*=2246822519u; u^=u>>13;
    ws[W_V + i] = (u&1)? invs : -invs;
  } else {
    ws[W_V + i] = 0.f;
  }
}

__global__ __launch_bounds__(256) void k_lz(float* ws, int j){
  int wid = blockIdx.x*4 + (threadIdx.x>>6);
  int lane = threadIdx.x & 63;
  int c, p, nbase;
  if (wid<1024){ c=0; p=wid;      nbase=0; }
  else if (wid<4096){ c=1; p=wid-1024; nbase=1024; }
  else { c=2; p=wid-4096; nbase=4096; }
  __shared__ float sc[3];
  __shared__ float red[3][4];
  if (threadIdx.x==0){
    if (j==0){ sc[0]=0.f; sc[1]=0.f; sc[2]=1.f; }
    else {
      const float* A = ws + W_ACC + (size_t)(j-1)*144 + (size_t)c*48;
      float a=0.f,g=0.f,n=0.f;
      #pragma unroll
      for(int b=0;b<16;b++){ a+=A[b]; g+=A[16+b]; n+=A[32+b]; }
      float beta = sqrtf(fmaxf(n - a*a - g*g, 1e-20f));
      sc[0]=a; sc[1]=g; sc[2]=1.f/beta;
    }
  }
  __syncthreads();
  float a=sc[0], g=sc[1], ib=sc[2];
  float* vcur       = ws + W_V + (size_t)(j%3)*6144 + nbase;
  const float* vm1  = ws + W_V + (size_t)((j+2)%3)*6144 + nbase;
  const float* vm2  = ws + W_V + (size_t)((j+1)%3)*6144 + nbase;
  const float* wprev= ws + W_V + (size_t)(3+((j+1)&1))*6144 + nbase;
  float* wcur       = ws + W_V + (size_t)(3+(j&1))*6144 + nbase;
  const int* wsi = (const int*)ws;
  const int* ptr = wsi + W_PTR;
  const int* cidx= wsi + W_CIDX;
  const float* val = ws + W_VAL;
  float wp = 0.f;
  #define GATHER(PP,CBB) { \
    const int* rp = ptr + PP; int e=rp[p+1]; \
    for (int k=rp[p]+lane; k<e; k+=64){ \
      int q = cidx[CBB+k]; float v = val[CBB+k]; \
      float vq = (j==0)? vcur[q] : (wprev[q] - a*vm1[q] - g*vm2[q])*ib; \
      wp += v*vq; \
    } }
  if (c==0){ GATHER(P_L0, CB_L0) }
  else if (c==1){ GATHER(P_L1D, CB_L1D) GATHER(P_L1U, CB_L1U) }
  else { GATHER(P_L2, CB_L2) }
  #undef GATHER
  wp = wredf(wp);
  int wv = threadIdx.x>>6;
  if (lane==0){
    float vp;
    if (j==0) vp = vcur[p];
    else { vp = (wprev[p] - a*vm1[p] - g*vm2[p])*ib; vcur[p] = vp; }
    wcur[p] = wp;
    red[0][wv]=vp*wp; red[1][wv]=vm1[p]*wp; red[2][wv]=wp*wp;
  }
  __syncthreads();
  if (threadIdx.x==0){
    float A=red[0][0]+red[0][1]+red[0][2]+red[0][3];
    float G=red[1][0]+red[1][1]+red[1][2]+red[1][3];
    float Nn=red[2][0]+red[2][1]+red[2][2]+red[2][3];
    int bkt = blockIdx.x & 15;
    float* acc = ws + W_ACC + (size_t)j*144 + (size_t)c*48;
    atomicAdd(acc +      bkt, A);
    atomicAdd(acc + 16 + bkt, G);
    atomicAdd(acc + 32 + bkt, Nn);
  }
}

__global__ void k_eig(float* ws){
  __shared__ float TAs[3][M_LZ], TBs[3][M_LZ];
  int c = threadIdx.x>>6, lane = threadIdx.x&63;
  if (c<3){
    for (int i=lane;i<M_LZ;i+=64){
      const float* A = ws + W_ACC + (size_t)i*144 + (size_t)c*48;
      float a=0.f,g=0.f,n=0.f;
      #pragma unroll
      for(int b=0;b<16;b++){ a+=A[b]; g+=A[16+b]; n+=A[32+b]; }
      TAs[c][i]=a;
      TBs[c][i]=sqrtf(fmaxf(n - a*a - g*g, 1e-20f));
    }
  }
  __syncthreads();
  if (c>=3) return;
  const float* TA = TAs[c];
  const float* TB = TBs[c];
  double lo=1e300, hi=-1e300;
  for (int i=lane;i<M_LZ;i+=64){
    double r=(i? fabs((double)TB[i-1]):0.0) + (i<M_LZ-1? fabs((double)TB[i]):0.0);
    lo = fmin(lo,(double)TA[i]-r); hi = fmax(hi,(double)TA[i]+r);
  }
  #pragma unroll
  for(int o=32;o;o>>=1){ lo=fmin(lo,__shfl_xor(lo,o,64)); hi=fmax(hi,__shfl_xor(hi,o,64)); }
  lo -= 1.0; hi += 1.0;
  for (int round=0; round<4; round++){
    double x = lo + (hi-lo)*(double)(lane+1)/65.0;
    double d = 1.0; int cnt=0;
    for (int i=0;i<M_LZ;i++){
      double bi = i? (double)TB[i-1] : 0.0;
      d = ((double)TA[i]-x) - bi*bi/d;
      if (d==0.0) d = -1e-300;
      if (d<0.0) cnt++;
    }
    double nlo = (cnt< M_LZ)? x : -1e300;
    double nhi = (cnt==M_LZ)? x :  1e300;
    #pragma unroll
    for(int o=32;o;o>>=1){ nlo=fmax(nlo,__shfl_xor(nlo,o,64)); nhi=fmin(nhi,__shfl_xor(nhi,o,64)); }
    if (nlo>-1e299) lo=nlo;
    if (nhi< 1e299) hi=nhi;
  }
  double lam = 0.5*(lo+hi);
  if (lane==0) ws[W_EPS+c] = (lam>0.0)? (float)(1.0/lam) : 0.1f;
}

__global__ void k_attn_uv(const float* z1, const float* wd, const float* wu, float* ws){
  int wid = blockIdx.x*4 + (threadIdx.x>>6);
  int lane = threadIdx.x & 63;
  if (wid>=3072) return;
  float2 x = ((const float2*)(z1 + (size_t)wid*128))[lane];
  float2 a0 = ((const float2*)wd)[lane];
  float2 a1 = ((const float2*)wd)[64+lane];
  float2 b0 = ((const float2*)wu)[lane];
  float2 b1 = ((const float2*)wu)[64+lane];
  float ud = x.x*a0.x + x.y*a0.y;
  float vd = x.x*a1.x + x.y*a1.y;
  float uu = x.x*b0.x + x.y*b0.y;
  float vu = x.x*b1.x + x.y*b1.y;
  ud=wredf(ud); vd=wredf(vd); uu=wredf(uu); vu=wredf(vu);
  if (lane==0){
    ws[W_UV+wid]=ud; ws[W_UV+3072+wid]=vd;
    ws[W_UV+6144+wid]=uu; ws[W_UV+9216+wid]=vu;
  }
}

__global__ __launch_bounds__(256) void k_harm(float* ws, const float* z0,const float* z1,const float* z2,int step){
  int wid = blockIdx.x*4 + (threadIdx.x>>6);
  int lane = threadIdx.x & 63;
  int c, p;
  if (wid<1024){ c=0; p=wid; }
  else if (wid<4096){ c=1; p=wid-1024; }
  else { c=2; p=wid-4096; }
  const float* z = (c==0)?z0:(c==1)?z1:z2;
  float eps = ws[W_EPS+c];
  size_t cb = (c==0)? 0 : (c==1)? (size_t)1024*128 : (size_t)4096*128;
  const float* in = (step==0)? z : ws + W_H + (size_t)((step-1)&1)*HBUF + cb;
  float* out; size_t ostride;
  if (step<15){ out = ws + W_H + (size_t)(step&1)*HBUF + cb; ostride=128; }
  else {
    if(c==0){ out=ws+W_SCAT+S0_OFF+256; ostride=384; }
    else if(c==1){ out=ws+W_SCAT+S1_OFF+512; ostride=640; }
    else { out=ws+W_SCAT+S2_OFF+256; ostride=384; }
  }
  const int* wsi=(const int*)ws;
  const int* ptr=wsi+W_PTR; const int* cidx=wsi+W_CIDX; const float* val=ws+W_VAL;
  float2 acc = ((const float2*)(in + (size_t)p*128))[lane];
  float2 s = {0.f,0.f};
  #define HGATHER(PP,CBB) { \
    const int* rp=ptr+PP; int e=rp[p+1]; \
    for(int k=rp[p];k<e;k++){ \
      float v=val[CBB+k]; int q=cidx[CBB+k]; \
      float2 xq=((const float2*)(in+(size_t)q*128))[lane]; \
      s.x+=v*xq.x; s.y+=v*xq.y; \
    } }
  if (c==0){ HGATHER(P_L0, CB_L0) }
  else if (c==1){ HGATHER(P_L1D, CB_L1D) HGATHER(P_L1U, CB_L1U) }
  else { HGATHER(P_L2, CB_L2) }
  #undef HGATHER
  acc.x -= eps*s.x; acc.y -= eps*s.y;
  ((float2*)(out + (size_t)p*ostride))[lane] = acc;
}

__global__ void k_spmm_fwd(float* ws, const float* z0,const float* z1,const float* z2,
                           const float* bd, const float* bu){
  int wid = blockIdx.x*4 + (threadIdx.x>>6);
  int lane = threadIdx.x & 63;
  if (wid>=18432) return;
  int task, p;
  if(wid<1024){task=0;p=wid;}
  else if(wid<2048){task=1;p=wid-1024;}
  else if(wid<5120){task=2;p=wid-2048;}
  else if(wid<8192){task=3;p=wid-5120;}
  else if(wid<11264){task=4;p=wid-8192;}
  else if(wid<13312){task=5;p=wid-11264;}
  else if(wid<16384){task=6;p=wid-13312;}
  else {task=7;p=wid-16384;}
  const int* wsi=(const int*)ws;
  const int* ptr=wsi+W_PTR; const int* cidx=wsi+W_CIDX; const float* val=ws+W_VAL;
  const float* in; const int* rp; int cb; float* out; int ostride;
  int mode=0; float Vp=0.f, bb=0.f; const float* U=nullptr;
  switch(task){
    case 0: rp=ptr+P_L0;  cb=CB_L0;  in=z0; out=ws+W_SCAT+S0_OFF+0;   ostride=384; break;
    case 1: rp=ptr+P_B1;  cb=CB_B1;  in=z1; out=ws+W_SCAT+S0_OFF+128; ostride=384; break;
    case 2: rp=ptr+P_L1D; cb=CB_L1D; in=z1; out=ws+W_SCAT+S1_OFF+0;   ostride=640;
            mode=1; U=ws+W_UV; Vp=ws[W_UV+3072+p]; bb=bd[0]; break;
    case 3: rp=ptr+P_L1U; cb=CB_L1U; in=z1; out=ws+W_SCAT+S1_OFF+128; ostride=640;
            mode=1; U=ws+W_UV+6144; Vp=ws[W_UV+9216+p]; bb=bu[0]; break;
    case 4: rp=ptr+P_B2;  cb=CB_B2;  in=z2; out=ws+W_SCAT+S1_OFF+384; ostride=640; break;
    case 5: rp=ptr+P_L2;  cb=CB_L2;  in=z2; out=ws+W_SCAT+S2_OFF+0;   ostride=384; break;
    case 6: rp=ptr+P_B1T; cb=CB_B1T; in=z0; out=ws+W_SCAT+S1_OFF+256; ostride=640; break;
    default:rp=ptr+P_B2T; cb=CB_B2T; in=z1; out=ws+W_SCAT+S2_OFF+128; ostride=384; break;
  }
  float2 s={0.f,0.f};
  int e=rp[p+1];
  for (int k=rp[p]; k<e; k++){
    int q = cidx[cb+k];
    float v;
    if (mode) v = 1.0f/(1.0f+__expf(-(U[q]+Vp+bb)));
    else v = val[cb+k];
    float2 xq = ((const float2*)(in+(size_t)q*128))[lane];
    s.x += v*xq.x; s.y += v*xq.y;
  }
  ((float2*)(out + (size_t)p*ostride))[lane] = s;
}

__global__ __launch_bounds__(256) void k_gemm(const float* S, const float* W, float* out, int M, int K){
  __shared__ float Sl[32][33];
  __shared__ float Wl[32][128];
  int t=threadIdx.x;
  int r0=blockIdx.x*32;
  int ty=t>>5, tx=t&31;
  float acc[4][4]={};
  for (int k0=0; k0<K; k0+=32){
    {
      int r=t>>3, kq=(t&7)*4;
      const float* src=S+(size_t)(r0+r)*K + k0+kq;
      Sl[r][kq]=src[0]; Sl[r][kq+1]=src[1]; Sl[r][kq+2]=src[2]; Sl[r][kq+3]=src[3];
    }
    {
      int kk=t>>4, cq=(t&15)*8;
      #pragma unroll
      for(int h=0;h<2;h++){
        const float* src=W+(size_t)(k0+kk+16*h)*128+cq;
        #pragma unroll
        for(int i=0;i<8;i++) Wl[kk+16*h][cq+i]=src[i];
      }
    }
    __syncthreads();
    #pragma unroll
    for(int k=0;k<32;k++){
      float sv[4], wv[4];
      #pragma unroll
      for(int i=0;i<4;i++) sv[i]=Sl[ty*4+i][k];
      #pragma unroll
      for(int i=0;i<4;i++) wv[i]=Wl[k][tx+32*i];
      #pragma unroll
      for(int a=0;a<4;a++)
        #pragma unroll
        for(int b2=0;b2<4;b2++) acc[a][b2]+=sv[a]*wv[b2];
    }
    __syncthreads();
  }
  #pragma unroll
  for(int a=0;a<4;a++)
    #pragma unroll
    for(int b2=0;b2<4;b2++){
      int r=r0+ty*4+a, col=tx+32*b2;
      out[(size_t)r*128+col]=fmaxf(acc[a][b2],0.f);
    }
}

// ---------------- host ----------------
extern "C" void kernel_launch(void* const* d_in, const int* in_sizes, int n_in,
                              void* d_out, int out_size, void* d_ws, size_t ws_size,
                              hipStream_t stream){
  const float* z0 =(const float*)d_in[0];
  const float* z1 =(const float*)d_in[1];
  const float* z2 =(const float*)d_in[2];
  const float* L0 =(const float*)d_in[3];
  const float* L1d=(const float*)d_in[4];
  const float* L1u=(const float*)d_in[5];
  const float* L2 =(const float*)d_in[6];
  const float* B1 =(const float*)d_in[7];
  const float* B2 =(const float*)d_in[8];
  const float* Wd =(const float*)d_in[9];
  const float* Wu =(const float*)d_in[10];
  const float* Wh =(const float*)d_in[11];
  const float* Wb1=(const float*)d_in[12];
  const float* Wb2=(const float*)d_in[13];
  const float* adw=(const float*)d_in[14];
  const float* adb=(const float*)d_in[15];
  const float* auw=(const float*)d_in[16];
  const float* aub=(const float*)d_in[17];
  float* ws=(float*)d_ws;
  int* wsi=(int*)d_ws;
  float* out=(float*)d_out;

  hipLaunchKernelGGL(k_wprep, dim3(64), dim3(256), 0, stream, Wd,Wu,Wh,Wb1,Wb2,ws);
  hipLaunchKernelGGL(k_count, dim3(3328), dim3(256), 0, stream, L0,L1d,L1u,L2,B1,B2, wsi+W_CNT);
  hipLaunchKernelGGL(k_prefix, dim3(8), dim3(256), 0, stream, wsi+W_CNT, wsi+W_PTR, wsi+W_CUR);
  hipLaunchKernelGGL(k_fill, dim3(3328), dim3(256), 0, stream, L0,L1d,L1u,L2,B1,B2, wsi+W_PTR, wsi+W_CIDX, ws+W_VAL);
  hipLaunchKernelGGL(k_fillT, dim3(1024), dim3(256), 0, stream, ws);

  void* args[] = { (void*)&ws, (void*)&z0, (void*)&z1, (void*)&z2,
                   (void*)&adw, (void*)&adb, (void*)&auw, (void*)&aub, (void*)&out };
  hipError_t cerr = hipLaunchCooperativeKernel(reinterpret_cast<void*>(k_solve),
                                               dim3(1024), dim3(256), args, 0, stream);
  if (cerr != hipSuccess){
    // -------- fallback: proven multi-kernel path (round 3) --------
    hipLaunchKernelGGL(k_init, dim3(72), dim3(256), 0, stream, ws);
    for (int j=0;j<M_LZ;j++)
      hipLaunchKernelGGL(k_lz, dim3(1536), dim3(256), 0, stream, ws, j);
    hipLaunchKernelGGL(k_eig, dim3(1), dim3(256), 0, stream, ws);
    hipLaunchKernelGGL(k_attn_uv, dim3(768), dim3(256), 0, stream, z1, adw, auw, ws);
    for (int s=0;s<16;s++)
      hipLaunchKernelGGL(k_harm, dim3(1536), dim3(256), 0, stream, ws, z0,z1,z2, s);
    hipLaunchKernelGGL(k_spmm_fwd, dim3(4608), dim3(256), 0, stream, ws, z0,z1,z2, adb, aub);
    hipLaunchKernelGGL(k_gemm, dim3(32), dim3(256), 0, stream, ws+W_SCAT+S0_OFF, ws+W_WCAT+WC0, out,          1024, 384);
    hipLaunchKernelGGL(k_gemm, dim3(96), dim3(256), 0, stream, ws+W_SCAT+S1_OFF, ws+W_WCAT+WC1, out+131072,   3072, 640);
    hipLaunchKernelGGL(k_gemm, dim3(64), dim3(256), 0, stream, ws+W_SCAT+S2_OFF, ws+W_WCAT+WC2, out+524288,   2048, 384);
  }
}

// Round 6
// 3274.806 us; speedup vs baseline: 4.4408x; 4.4408x over previous
//
#include <hip/hip_runtime.h>
#include <string.h>

// ---------------- problem constants ----------------
constexpr int M_LZ = 96;           // Lanczos steps

// CSR capacity per matrix (expected nnz * ~1.25)
constexpr int CAP_L0 = 26240, CAP_L1 = 118016, CAP_L2 = 52480, CAP_B1 = 39360, CAP_B2 = 78720;
constexpr int CB_L0 = 0;
constexpr int CB_L1D = CB_L0 + CAP_L0;
constexpr int CB_L1U = CB_L1D + CAP_L1;
constexpr int CB_L2  = CB_L1U + CAP_L1;
constexpr int CB_B1  = CB_L2 + CAP_L2;
constexpr int CB_B2  = CB_B1 + CAP_B1;
constexpr int CAP_TOT= CB_B2 + CAP_B2;   // 432832
constexpr int CB_B1T = CAP_TOT;
constexpr int CB_B2T = CB_B1T + CAP_B1;
constexpr int CAP_TOT2 = CB_B2T + CAP_B2; // 550912

// rowptr offsets (ints) within W_PTR region
constexpr int P_L0=0, P_L1D=1025, P_L1U=4098, P_L2=7171, P_B1=9220, P_B2=10245;
constexpr int P_B1T=13320, P_B2T=16393;   // region size 18444
// row-count offsets within W_CNT region
constexpr int C_L0=0, C_L1D=1024, C_L1U=4096, C_L2=7168, C_B1=9216, C_B2=10240;
constexpr int C_B1T=13312, C_B2T=16384;   // region size 18432

// workspace layout (units: 4-byte words)
constexpr size_t W_CNT = 0;                         // 18432 ints
constexpr size_t W_PTR = 18432;                     // 18444 ints
constexpr size_t W_CUR = W_PTR + 18444;             // 5120 ints
constexpr size_t W_CIDX= W_CUR + 5120;              // CAP_TOT2 ints
constexpr size_t W_VAL = W_CIDX + CAP_TOT2;         // CAP_TOT2 floats
constexpr size_t W_V   = W_VAL + CAP_TOT2;          // 5 slots * 6144 (v0,v1,v2, w0,w1)
constexpr size_t W_ACC = W_V + 5*6144;              // M_LZ*144 (16-bucket dot accumulators)
constexpr size_t W_EPS = W_ACC + (size_t)M_LZ*144;  // 4
constexpr size_t W_UV  = W_EPS + 4;                 // 4*3072 (U_d,V_d,U_u,V_u)
constexpr size_t HBUF  = (size_t)6144*128;
constexpr size_t W_H   = W_UV + 4*3072;             // 2 ping-pong harmonic buffers
constexpr size_t W_SCAT= W_H + 2*HBUF;
constexpr size_t S0_OFF= 0;                          // 1024 x 384
constexpr size_t S1_OFF= (size_t)1024*384;           // 3072 x 640
constexpr size_t S2_OFF= S1_OFF + (size_t)3072*640;  // 2048 x 384
constexpr size_t SCAT_TOT = S2_OFF + (size_t)2048*384;
constexpr size_t W_WCAT= W_SCAT + SCAT_TOT;          // 1408*128 concatenated weights
constexpr size_t WC0=0, WC1=(size_t)384*128, WC2=WC1+(size_t)640*128;
constexpr size_t W_BAR = W_WCAT + (size_t)1408*128;  // 32 ints: 16 leaves, root, rel

__device__ __forceinline__ float wredf(float v){
  #pragma unroll
  for(int o=32;o;o>>=1) v += __shfl_xor(v,o,64);
  return v;
}
__device__ __forceinline__ int wredi(int v){
  #pragma unroll
  for(int o=32;o;o>>=1) v += __shfl_xor(v,o,64);
  return v;
}

// ---- coherent (agent-scope, L2-bypassing) access helpers for cross-step data ----
__device__ __forceinline__ float ldc(const float* p){
  return __hip_atomic_load(p, __ATOMIC_RELAXED, __HIP_MEMORY_SCOPE_AGENT);
}
__device__ __forceinline__ void stc(float* p, float v){
  __hip_atomic_store(p, v, __ATOMIC_RELAXED, __HIP_MEMORY_SCOPE_AGENT);
}
__device__ __forceinline__ float2 ldc2(const float* p){
  unsigned long long u = __hip_atomic_load((const unsigned long long*)p,
                          __ATOMIC_RELAXED, __HIP_MEMORY_SCOPE_AGENT);
  float2 r; memcpy(&r,&u,8); return r;
}
__device__ __forceinline__ void stc2(float* p, float2 v){
  unsigned long long u; memcpy(&u,&v,8);
  __hip_atomic_store((unsigned long long*)p, u, __ATOMIC_RELAXED, __HIP_MEMORY_SCOPE_AGENT);
}

// ---- lightweight grid barrier: 16-leaf tree, monotonic counters, no cache flush ----
// Relies on: all cross-step data uses agent-scope (sc1) ops; s_barrier drains vmem;
// control dependence on the flag load orders subsequent coherent loads.
__device__ __forceinline__ void gbar(int* bar, int ph, int b){
  __syncthreads();
  if (threadIdx.x==0){
    __builtin_amdgcn_s_waitcnt(0);
    int lv = __hip_atomic_fetch_add(bar + (b&15), 1, __ATOMIC_RELAXED, __HIP_MEMORY_SCOPE_AGENT);
    if (lv == 64*(ph+1)-1){
      int rv = __hip_atomic_fetch_add(bar + 16, 1, __ATOMIC_RELAXED, __HIP_MEMORY_SCOPE_AGENT);
      if (rv == 16*(ph+1)-1)
        __hip_atomic_store(bar + 17, ph+1, __ATOMIC_RELAXED, __HIP_MEMORY_SCOPE_AGENT);
    }
    while (__hip_atomic_load(bar + 17, __ATOMIC_RELAXED, __HIP_MEMORY_SCOPE_AGENT) < ph+1)
      __builtin_amdgcn_s_sleep(2);
  }
  __syncthreads();
}

// ---------------- weight prep + zeroing of counters/accumulators/barrier ----------------
__global__ void k_wprep(const float* Wd,const float* Wu,const float* Wh,
                        const float* Wb1,const float* Wb2, float* ws){
  int t = blockIdx.x*256 + threadIdx.x;
  if (t >= 16384) return;
  int* wsi = (int*)ws;
  if (t < 5120) wsi[W_CNT + 13312 + t] = 0;          // transpose col counters
  if (t < 5120) wsi[W_CUR + t] = 0;                  // cursors
  if (t < 32)   wsi[W_BAR + t] = 0;                  // grid barrier state
  if (t < (int)(M_LZ*144)) ws[W_ACC + t] = 0.f;      // lanczos dot buckets
  float sd = Wd[t]  + Wd[16384+t]  + Wd[32768+t];
  float su = Wu[t]  + Wu[16384+t]  + Wu[32768+t];
  float s1 = Wb1[t] + Wb1[16384+t] + Wb1[32768+t];
  float s2 = Wb2[t] + Wb2[16384+t] + Wb2[32768+t];
  float wh = Wh[t];
  float* W0 = ws + W_WCAT + WC0;
  float* W1 = ws + W_WCAT + WC1;
  float* W2 = ws + W_WCAT + WC2;
  W0[t]=sd; W0[16384+t]=s1; W0[32768+t]=wh;                       // [Wd;Wb1;Wh]
  W1[t]=sd; W1[16384+t]=su; W1[32768+t]=s1; W1[49152+t]=s2; W1[65536+t]=wh; // [Wd;Wu;Wb1;Wb2;Wh]
  W2[t]=su; W2[16384+t]=s2; W2[32768+t]=wh;                       // [Wu;Wb2;Wh]
}

// ---------------- CSR extraction ----------------
__device__ __forceinline__ void mat_meta(int wid, const float* L0,const float* L1d,const float* L1u,
    const float* L2,const float* B1,const float* B2,
    const float*& M,int& ncol,int& lrow,int& co,int& po,int& cb,int& cap,int& tco){
  if (wid < 1024){ M=L0;  ncol=1024; lrow=wid;        co=C_L0;  po=P_L0;  cb=CB_L0;  cap=CAP_L0; tco=-1; }
  else if (wid < 4096){ M=L1d; ncol=3072; lrow=wid-1024;  co=C_L1D; po=P_L1D; cb=CB_L1D; cap=CAP_L1; tco=-1; }
  else if (wid < 7168){ M=L1u; ncol=3072; lrow=wid-4096;  co=C_L1U; po=P_L1U; cb=CB_L1U; cap=CAP_L1; tco=-1; }
  else if (wid < 9216){ M=L2;  ncol=2048; lrow=wid-7168;  co=C_L2;  po=P_L2;  cb=CB_L2;  cap=CAP_L2; tco=-1; }
  else if (wid < 10240){ M=B1; ncol=3072; lrow=wid-9216;  co=C_B1;  po=P_B1;  cb=CB_B1;  cap=CAP_B1; tco=C_B1T; }
  else { M=B2; ncol=2048; lrow=wid-10240; co=C_B2;  po=P_B2;  cb=CB_B2;  cap=CAP_B2; tco=C_B2T; }
}

__global__ void k_count(const float* L0,const float* L1d,const float* L1u,const float* L2,
                        const float* B1,const float* B2,int* cnt){
  int wid = blockIdx.x*4 + (threadIdx.x>>6);
  int lane = threadIdx.x & 63;
  if (wid >= 13312) return;
  const float* M; int ncol,lrow,co,po,cb,cap,tco;
  mat_meta(wid,L0,L1d,L1u,L2,B1,B2,M,ncol,lrow,co,po,cb,cap,tco);
  const float4* row4 = (const float4*)(M + (size_t)lrow*ncol);
  int c = 0;
  for (int j0=0; j0<ncol; j0+=256){
    float4 v = row4[(j0>>2)+lane];
    int n0=v.x!=0.f, n1=v.y!=0.f, n2=v.z!=0.f, n3=v.w!=0.f;
    c += n0+n1+n2+n3;
    if (tco>=0){
      int jb = j0 + lane*4;
      if (n0) atomicAdd(cnt+tco+jb,   1);
      if (n1) atomicAdd(cnt+tco+jb+1, 1);
      if (n2) atomicAdd(cnt+tco+jb+2, 1);
      if (n3) atomicAdd(cnt+tco+jb+3, 1);
    }
  }
  c = wredi(c);
  if (lane==0) cnt[co+lrow] = c;
}

__global__ void k_prefix(const int* cnt, int* ptr, int* cur){
  __shared__ int lds[257];
  const int rows[8]={1024,3072,3072,2048,1024,3072,3072,2048};
  const int cofs[8]={C_L0,C_L1D,C_L1U,C_L2,C_B1,C_B2,C_B1T,C_B2T};
  const int pofs[8]={P_L0,P_L1D,P_L1U,P_L2,P_B1,P_B2,P_B1T,P_B2T};
  int b=blockIdx.x, t=threadIdx.x;
  int R=rows[b]; const int* c=cnt+cofs[b]; int* p=ptr+pofs[b];
  int* cc = (b==6)? cur : (b==7)? cur+3072 : nullptr;
  int chunk=(R+255)/256;
  int lo=t*chunk, hi=min(R,lo+chunk);
  int s=0;
  for(int i=lo;i<hi;i++) s+=c[i];
  lds[t]=s; __syncthreads();
  if(t==0){ int run=0; for(int i=0;i<256;i++){int x=lds[i];lds[i]=run;run+=x;} lds[256]=run; }
  __syncthreads();
  int run=lds[t];
  for(int i=lo;i<hi;i++){ p[i]=run; if(cc) cc[i]=run; run+=c[i]; }
  if(t==0) p[R]=lds[256];
}

__global__ void k_fill(const float* L0,const float* L1d,const float* L1u,const float* L2,
                       const float* B1,const float* B2,const int* ptr,int* cidx,float* val){
  int wid = blockIdx.x*4 + (threadIdx.x>>6);
  int lane = threadIdx.x & 63;
  if (wid >= 13312) return;
  const float* M; int ncol,lrow,co,po,cb,cap,tco;
  mat_meta(wid,L0,L1d,L1u,L2,B1,B2,M,ncol,lrow,co,po,cb,cap,tco);
  const float4* row4 = (const float4*)(M + (size_t)lrow*ncol);
  int base = ptr[po+lrow];
  int run = 0;
  for (int j0=0; j0<ncol; j0+=256){
    float4 v = row4[(j0>>2)+lane];
    int n0=v.x!=0.f, n1=v.y!=0.f, n2=v.z!=0.f, n3=v.w!=0.f;
    int local = n0+n1+n2+n3;
    int incl = local;
    #pragma unroll
    for (int o=1;o<64;o<<=1){
      int tmp = __shfl_up(incl,o,64);
      if (lane>=o) incl += tmp;
    }
    int tot = __shfl(incl,63,64);
    int pos = base + run + incl - local;
    int jb = j0 + lane*4;
    if (n0){ if(pos<cap){cidx[cb+pos]=jb;   val[cb+pos]=v.x;} pos++; }
    if (n1){ if(pos<cap){cidx[cb+pos]=jb+1; val[cb+pos]=v.y;} pos++; }
    if (n2){ if(pos<cap){cidx[cb+pos]=jb+2; val[cb+pos]=v.z;} pos++; }
    if (n3){ if(pos<cap){cidx[cb+pos]=jb+3; val[cb+pos]=v.w;} pos++; }
    run += tot;
  }
}

// ---------------- CSR -> CSC (CSR of B1^T, B2^T) via cursor atomics ----------------
__global__ void k_fillT(float* ws){
  int wid = blockIdx.x*4 + (threadIdx.x>>6);
  int lane = threadIdx.x & 63;
  if (wid >= 4096) return;
  int* wsi=(int*)ws;
  const int* ptr=wsi+W_PTR; int* cidx=wsi+W_CIDX; float* val=ws+W_VAL;
  int* cur=wsi+W_CUR;
  if (wid < 1024){           // B1 rows -> B1T
    int r=wid;
    int e=ptr[P_B1+r+1];
    for(int k=ptr[P_B1+r]+lane;k<e;k+=64){
      int c=cidx[CB_B1+k]; float v=val[CB_B1+k];
      int pos=atomicAdd(cur+c,1);
      cidx[CB_B1T+pos]=r; val[CB_B1T+pos]=v;
    }
  } else {                   // B2 rows -> B2T
    int r=wid-1024;
    int e=ptr[P_B2+r+1];
    for(int k=ptr[P_B2+r]+lane;k<e;k+=64){
      int c=cidx[CB_B2+k]; float v=val[CB_B2+k];
      int pos=atomicAdd(cur+3072+c,1);
      cidx[CB_B2T+pos]=r; val[CB_B2T+pos]=v;
    }
  }
}

// ================= FUSED PERSISTENT SOLVER (regular launch, custom barrier) =======
// 1024 blocks x 256 threads = exactly 4 blocks/CU -> all co-resident.
// Cross-step data (W_V, W_ACC, W_EPS, W_UV, W_H, W_SCAT) -> agent-scope sc1 ops.
// Read-only data (CSR, z*, weights) -> normal cached loads (L2 reuse preserved).
__global__ __launch_bounds__(256,4) void k_solve(float* ws,
    const float* z0,const float* z1,const float* z2,
    const float* adw,const float* adb,const float* auw,const float* aub,
    float* out){
  const int b = blockIdx.x, t = threadIdx.x;
  const int wv = t>>6, lane = t&63;
  const int gw = b*4 + wv;                 // 0..4095
  int* bar = (int*)ws + W_BAR;
  int ph = 0;
  const int* wsi=(const int*)ws;
  const int* ptr=wsi+W_PTR; const int* cidx=wsi+W_CIDX; const float* val=ws+W_VAL;

  __shared__ float smem[2592];             // 10368 B, aliased per phase
  float* sABG = smem;                      // [3][3]   (phase B)
  float* redm = smem + 12;                 // [2][3][4](phase B)
  float* sp   = smem + 40;                 // [48][3]  (phase B)
  float* TTa  = smem;                      // [3][96]  (phase C, block 0)
  float* TTb  = smem + 288;                // [3][96]
  float* Sl   = smem;                      // [32][17] (phase E)
  float* Wl   = smem + 544;                // [16][128]

  // ---- Phase A: init lanczos vectors + attention U,V ----
  { int i = b*256+t;
    if (i < 6144){
      float invs = (i<1024)?0.03125f:(i<4096)?0.0180421959f:0.0220970869f;
      unsigned u=(unsigned)i*2654435761u; u^=u>>16; u*=2246822519u; u^=u>>13;
      stc(ws+W_V+i, (u&1)?invs:-invs);       // v0 (slot 0)
    } else if (i < 18432){
      stc(ws+W_V+i, 0.f);                    // v-slots 1,2 = 0
    }
  }
  if (gw < 3072){
    float2 x  = ((const float2*)(z1+(size_t)gw*128))[lane];
    float2 a0 = ((const float2*)adw)[lane];
    float2 a1 = ((const float2*)adw)[64+lane];
    float2 b0 = ((const float2*)auw)[lane];
    float2 b1 = ((const float2*)auw)[64+lane];
    float ud=x.x*a0.x+x.y*a0.y, vd=x.x*a1.x+x.y*a1.y;
    float uu=x.x*b0.x+x.y*b0.y, vu=x.x*b1.x+x.y*b1.y;
    ud=wredf(ud); vd=wredf(vd); uu=wredf(uu); vu=wredf(vu);
    if(lane==0){ stc(ws+W_UV+gw,ud); stc(ws+W_UV+3072+gw,vd);
                 stc(ws+W_UV+6144+gw,uu); stc(ws+W_UV+9216+gw,vu); }
  }
  gbar(bar, ph++, b);

  // row ownership (block-uniform: boundaries 1024,4096 are multiples of 4)
  const int cA = (b<256)?0:1;          // complex of row1
  const int p1 = gw - (cA?1024:0);
  const int nb1 = cA?1024:0;
  const bool has2 = (b<512);           // row2 = gw+4096 in [4096,6144)
  const int p2 = gw;

  // ---- Phase B: 96 merged Lanczos steps, 1 barrier each ----
  for (int j=0;j<M_LZ;j++){
    if (j==0){
      if (t<3){ sABG[t*3+0]=0.f; sABG[t*3+1]=0.f; sABG[t*3+2]=1.f; }
    } else {
      if (t<48){
        int c=t>>4, bk=t&15;
        const float* A = ws + W_ACC + (size_t)(j-1)*144 + c*48;
        sp[t*3+0]=ldc(A+bk); sp[t*3+1]=ldc(A+16+bk); sp[t*3+2]=ldc(A+32+bk);
      }
      __syncthreads();
      if (t<3){
        float a=0.f,g=0.f,n=0.f;
        #pragma unroll
        for(int i=0;i<16;i++){ a+=sp[(t*16+i)*3+0]; g+=sp[(t*16+i)*3+1]; n+=sp[(t*16+i)*3+2]; }
        float beta = sqrtf(fmaxf(n-a*a-g*g,1e-20f));
        sABG[t*3+0]=a; sABG[t*3+1]=g; sABG[t*3+2]=1.f/beta;
      }
    }
    __syncthreads();
    auto dorow = [&](int c,int p,int nbase,int grp){
      float a=sABG[c*3+0], g=sABG[c*3+1], ib=sABG[c*3+2];
      float* vcur       = ws + W_V + (size_t)(j%3)*6144 + nbase;
      const float* vm1  = ws + W_V + (size_t)((j+2)%3)*6144 + nbase;
      const float* vm2  = ws + W_V + (size_t)((j+1)%3)*6144 + nbase;
      const float* wprev= ws + W_V + (size_t)(3+((j+1)&1))*6144 + nbase;
      float* wcur       = ws + W_V + (size_t)(3+(j&1))*6144 + nbase;
      float wp=0.f;
      #define GATHER(PP,CBB) { \
        const int* rp = ptr + PP; int e=rp[p+1]; \
        for (int k=rp[p]+lane; k<e; k+=64){ \
          int q = cidx[CBB+k]; float v = val[CBB+k]; \
          float vq = (j==0)? ldc(vcur+q) : (ldc(wprev+q) - a*ldc(vm1+q) - g*ldc(vm2+q))*ib; \
          wp += v*vq; \
        } }
      if (c==0){ GATHER(P_L0, CB_L0) }
      else if (c==1){ GATHER(P_L1D, CB_L1D) GATHER(P_L1U, CB_L1U) }
      else { GATHER(P_L2, CB_L2) }
      #undef GATHER
      wp = wredf(wp);
      if (lane==0){
        float vp;
        if (j==0) vp = ldc(vcur+p);
        else { vp = (ldc(wprev+p) - a*ldc(vm1+p) - g*ldc(vm2+p))*ib; stc(vcur+p, vp); }
        stc(wcur+p, wp);
        redm[grp*12 + 0*4 + wv]=vp*wp;
        redm[grp*12 + 1*4 + wv]=ldc(vm1+p)*wp;
        redm[grp*12 + 2*4 + wv]=wp*wp;
      }
    };
    dorow(cA, p1, nb1, 0);
    if (has2) dorow(2, p2, 4096, 1);
    __syncthreads();
    if (t==0){
      int bkt = b & 15;
      float* acc = ws + W_ACC + (size_t)j*144;
      float A0=redm[0]+redm[1]+redm[2]+redm[3];
      float G0=redm[4]+redm[5]+redm[6]+redm[7];
      float N0=redm[8]+redm[9]+redm[10]+redm[11];
      atomicAdd(acc + cA*48 +      bkt, A0);
      atomicAdd(acc + cA*48 + 16 + bkt, G0);
      atomicAdd(acc + cA*48 + 32 + bkt, N0);
      if (has2){
        float A2=redm[12]+redm[13]+redm[14]+redm[15];
        float G2=redm[16]+redm[17]+redm[18]+redm[19];
        float N2=redm[20]+redm[21]+redm[22]+redm[23];
        atomicAdd(acc + 2*48 +      bkt, A2);
        atomicAdd(acc + 2*48 + 16 + bkt, G2);
        atomicAdd(acc + 2*48 + 32 + bkt, N2);
      }
    }
    gbar(bar, ph++, b);
  }

  // ---- Phase C: eig (block 0) + forward SpMMs (all blocks) ----
  if (b==0){
    if (t<192){
      int c=t>>6;
      for (int i=lane;i<M_LZ;i+=64){
        const float* A = ws + W_ACC + (size_t)i*144 + c*48;
        float a=0.f,g=0.f,n=0.f;
        #pragma unroll
        for(int k2=0;k2<16;k2++){ a+=ldc(A+k2); g+=ldc(A+16+k2); n+=ldc(A+32+k2); }
        TTa[c*M_LZ+i]=a; TTb[c*M_LZ+i]=sqrtf(fmaxf(n-a*a-g*g,1e-20f));
      }
    }
    __syncthreads();
    if (t<192){
      int c=t>>6;
      const float* TA=TTa+c*M_LZ; const float* TB=TTb+c*M_LZ;
      double lo=1e300, hi=-1e300;
      for (int i=lane;i<M_LZ;i+=64){
        double r=(i? fabs((double)TB[i-1]):0.0) + (i<M_LZ-1? fabs((double)TB[i]):0.0);
        lo=fmin(lo,(double)TA[i]-r); hi=fmax(hi,(double)TA[i]+r);
      }
      #pragma unroll
      for(int o=32;o;o>>=1){ lo=fmin(lo,__shfl_xor(lo,o,64)); hi=fmax(hi,__shfl_xor(hi,o,64)); }
      lo -= 1.0; hi += 1.0;
      for (int round=0; round<4; round++){
        double x = lo + (hi-lo)*(double)(lane+1)/65.0;
        double d = 1.0; int cnt2=0;
        for (int i=0;i<M_LZ;i++){
          double bi = i? (double)TB[i-1] : 0.0;
          d = ((double)TA[i]-x) - bi*bi/d;
          if (d==0.0) d = -1e-300;
          if (d<0.0) cnt2++;
        }
        double nlo = (cnt2< M_LZ)? x : -1e300;
        double nhi = (cnt2==M_LZ)? x :  1e300;
        #pragma unroll
        for(int o=32;o;o>>=1){ nlo=fmax(nlo,__shfl_xor(nlo,o,64)); nhi=fmin(nhi,__shfl_xor(nhi,o,64)); }
        if (nlo>-1e299) lo=nlo;
        if (nhi< 1e299) hi=nhi;
      }
      double lam = 0.5*(lo+hi);
      if (lane==0) stc(ws+W_EPS+c, (lam>0.0)? (float)(1.0/lam) : 0.1f);
    }
  }
  // forward SpMMs (tasks 0..18431, incl. attention-valued + transposes)
  for (int wid2 = gw; wid2 < 18432; wid2 += 4096){
    int task,p;
    if(wid2<1024){task=0;p=wid2;}
    else if(wid2<2048){task=1;p=wid2-1024;}
    else if(wid2<5120){task=2;p=wid2-2048;}
    else if(wid2<8192){task=3;p=wid2-5120;}
    else if(wid2<11264){task=4;p=wid2-8192;}
    else if(wid2<13312){task=5;p=wid2-11264;}
    else if(wid2<16384){task=6;p=wid2-13312;}
    else {task=7;p=wid2-16384;}
    const float* in; const int* rp; int cb2; float* outp; int ostride;
    int mode=0; float Vp=0.f, bb=0.f; const float* U=nullptr;
    switch(task){
      case 0: rp=ptr+P_L0;  cb2=CB_L0;  in=z0; outp=ws+W_SCAT+S0_OFF+0;   ostride=384; break;
      case 1: rp=ptr+P_B1;  cb2=CB_B1;  in=z1; outp=ws+W_SCAT+S0_OFF+128; ostride=384; break;
      case 2: rp=ptr+P_L1D; cb2=CB_L1D; in=z1; outp=ws+W_SCAT+S1_OFF+0;   ostride=640;
              mode=1; U=ws+W_UV; Vp=ldc(ws+W_UV+3072+p); bb=adb[0]; break;
      case 3: rp=ptr+P_L1U; cb2=CB_L1U; in=z1; outp=ws+W_SCAT+S1_OFF+128; ostride=640;
              mode=1; U=ws+W_UV+6144; Vp=ldc(ws+W_UV+9216+p); bb=aub[0]; break;
      case 4: rp=ptr+P_B2;  cb2=CB_B2;  in=z2; outp=ws+W_SCAT+S1_OFF+384; ostride=640; break;
      case 5: rp=ptr+P_L2;  cb2=CB_L2;  in=z2; outp=ws+W_SCAT+S2_OFF+0;   ostride=384; break;
      case 6: rp=ptr+P_B1T; cb2=CB_B1T; in=z0; outp=ws+W_SCAT+S1_OFF+256; ostride=640; break;
      default:rp=ptr+P_B2T; cb2=CB_B2T; in=z1; outp=ws+W_SCAT+S2_OFF+128; ostride=384; break;
    }
    float2 s={0.f,0.f};
    int e=rp[p+1];
    for (int k=rp[p]; k<e; k++){
      int q = cidx[cb2+k];
      float v;
      if (mode) v = 1.0f/(1.0f+__expf(-(ldc(U+q)+Vp+bb)));
      else v = val[cb2+k];
      float2 xq = ((const float2*)(in+(size_t)q*128))[lane];   // z: normal cached
      s.x += v*xq.x; s.y += v*xq.y;
    }
    stc2(outp + (size_t)p*ostride + 2*lane, s);
  }
  gbar(bar, ph++, b);

  // ---- Phase D: 16 harmonic steps, 1 barrier each ----
  auto harm_row = [&](int c,int p,int step){
    const float* z = (c==0)?z0:(c==1)?z1:z2;
    float eps = ldc(ws+W_EPS+c);
    size_t cb2 = (c==0)? 0 : (c==1)? (size_t)1024*128 : (size_t)4096*128;
    const float* in = ws + W_H + (size_t)((step-1)&1)*HBUF + cb2;  // step>0
    float* outp; size_t ostride;
    if (step<15){ outp = ws + W_H + (size_t)(step&1)*HBUF + cb2; ostride=128; }
    else {
      if(c==0){ outp=ws+W_SCAT+S0_OFF+256; ostride=384; }
      else if(c==1){ outp=ws+W_SCAT+S1_OFF+512; ostride=640; }
      else { outp=ws+W_SCAT+S2_OFF+256; ostride=384; }
    }
    float2 acc, s={0.f,0.f};
    if (step==0) acc = ((const float2*)(z + (size_t)p*128))[lane];
    else         acc = ldc2(in + (size_t)p*128 + 2*lane);
    #define HGATHER(PP,CBB) { \
      const int* rp=ptr+PP; int e=rp[p+1]; \
      for(int k=rp[p];k<e;k++){ \
        float v=val[CBB+k]; int q=cidx[CBB+k]; \
        float2 xq; \
        if (step==0) xq = ((const float2*)(z+(size_t)q*128))[lane]; \
        else         xq = ldc2(in+(size_t)q*128 + 2*lane); \
        s.x+=v*xq.x; s.y+=v*xq.y; \
      } }
    if (c==0){ HGATHER(P_L0, CB_L0) }
    else if (c==1){ HGATHER(P_L1D, CB_L1D) HGATHER(P_L1U, CB_L1U) }
    else { HGATHER(P_L2, CB_L2) }
    #undef HGATHER
    acc.x -= eps*s.x; acc.y -= eps*s.y;
    stc2(outp + (size_t)p*ostride + 2*lane, acc);
  };
  for (int s=0;s<16;s++){
    harm_row(cA, p1, s);
    if (has2) harm_row(2, p2, s);
    gbar(bar, ph++, b);
  }

  // ---- Phase E: projection GEMMs (blocks 0..191), K-tile 16 ----
  if (b < 192){
    const float* S; const float* W; float* outp; int K; int blk;
    if (b<32){       S=ws+W_SCAT+S0_OFF; W=ws+W_WCAT+WC0; outp=out;        K=384; blk=b; }
    else if (b<128){ S=ws+W_SCAT+S1_OFF; W=ws+W_WCAT+WC1; outp=out+131072; K=640; blk=b-32; }
    else {           S=ws+W_SCAT+S2_OFF; W=ws+W_WCAT+WC2; outp=out+524288; K=384; blk=b-128; }
    int r0=blk*32;
    int ty=t>>5, tx=t&31;
    float acc[4][4]={};
    for (int k0=0; k0<K; k0+=16){
      {
        int r=t>>3, kq=(t&7)*2;
        const float* src=S+(size_t)(r0+r)*K + k0+kq;
        Sl[r*17+kq]=ldc(src); Sl[r*17+kq+1]=ldc(src+1);
      }
      {
        int kk=t>>4, cq=(t&15)*8;
        const float* src=W+(size_t)(k0+kk)*128+cq;
        #pragma unroll
        for(int i=0;i<8;i++) Wl[kk*128+cq+i]=src[i];
      }
      __syncthreads();
      #pragma unroll
      for(int k=0;k<16;k++){
        float sv[4], wvv[4];
        #pragma unroll
        for(int i=0;i<4;i++) sv[i]=Sl[(ty*4+i)*17+k];
        #pragma unroll
        for(int i=0;i<4;i++) wvv[i]=Wl[k*128+tx+32*i];
        #pragma unroll
        for(int a=0;a<4;a++)
          #pragma unroll
          for(int b2=0;b2<4;b2++) acc[a][b2]+=sv[a]*wvv[b2];
      }
      __syncthreads();
    }
    #pragma unroll
    for(int a=0;a<4;a++)
      #pragma unroll
      for(int b2=0;b2<4;b2++){
        int r=r0+ty*4+a, col=tx+32*b2;
        outp[(size_t)r*128+col]=fmaxf(acc[a][b2],0.f);
      }
  }
}

// ---------------- host ----------------
extern "C" void kernel_launch(void* const* d_in, const int* in_sizes, int n_in,
                              void* d_out, int out_size, void* d_ws, size_t ws_size,
                              hipStream_t stream){
  const float* z0 =(const float*)d_in[0];
  const float* z1 =(const float*)d_in[1];
  const float* z2 =(const float*)d_in[2];
  const float* L0 =(const float*)d_in[3];
  const float* L1d=(const float*)d_in[4];
  const float* L1u=(const float*)d_in[5];
  const float* L2 =(const float*)d_in[6];
  const float* B1 =(const float*)d_in[7];
  const float* B2 =(const float*)d_in[8];
  const float* Wd =(const float*)d_in[9];
  const float* Wu =(const float*)d_in[10];
  const float* Wh =(const float*)d_in[11];
  const float* Wb1=(const float*)d_in[12];
  const float* Wb2=(const float*)d_in[13];
  const float* adw=(const float*)d_in[14];
  const float* adb=(const float*)d_in[15];
  const float* auw=(const float*)d_in[16];
  const float* aub=(const float*)d_in[17];
  float* ws=(float*)d_ws;
  int* wsi=(int*)d_ws;
  float* out=(float*)d_out;

  hipLaunchKernelGGL(k_wprep, dim3(64), dim3(256), 0, stream, Wd,Wu,Wh,Wb1,Wb2,ws);
  hipLaunchKernelGGL(k_count, dim3(3328), dim3(256), 0, stream, L0,L1d,L1u,L2,B1,B2, wsi+W_CNT);
  hipLaunchKernelGGL(k_prefix, dim3(8), dim3(256), 0, stream, wsi+W_CNT, wsi+W_PTR, wsi+W_CUR);
  hipLaunchKernelGGL(k_fill, dim3(3328), dim3(256), 0, stream, L0,L1d,L1u,L2,B1,B2, wsi+W_PTR, wsi+W_CIDX, ws+W_VAL);
  hipLaunchKernelGGL(k_fillT, dim3(1024), dim3(256), 0, stream, ws);
  hipLaunchKernelGGL(k_solve, dim3(1024), dim3(256), 0, stream,
                     ws, z0, z1, z2, adw, adb, auw, aub, out);
}